// Round 4
// baseline (141.852 us; speedup 1.0000x reference)
//
#include <hip/hip_runtime.h>

// CRITICAL: hipcc defaults to -ffp-contract=fast-honor-pragmas, and HIP's
// __fmul_rn/__fadd_rn are PLAIN OPERATORS (not contraction barriers like
// CUDA). This pragma is what actually guarantees mul/add are not fused into
// v_fmac, so our rounding matches numpy's exactly.
#pragma clang fp contract(off)

// Problem constants (from reference): B=4, N=16384, M=4096, D=64
#define BB 4
#define NN 16384
#define MM 4096
#define DD 64
#define BN (BB * NN)              // 65536 points
#define FEATS_OFF 0               // feats: BN*DD floats
#define IDS_OFF (BN * DD)         // ids:   BN floats (ints stored as float)
#define PC_OFF (IDS_OFF + BN)     // pc:    BN*3 floats passthrough

#define PTS_PER_BLOCK 64
#define KPC (MM / 4)              // 1024 keys per chunk-lane

// NUMERICS (target: numpy fp32 replay of the reference):
//  - cross: np.einsum npyv path, count=3 -> one partial-vector muladd
//    (baseline SSE2: separate mul, exact +0) + hadd horizontal sum
//    == rn(rn(px*kx + py*ky) + pz*kz)  (ascending-plain, NO FMA).
//  - p_sq/k_sq: np.sum pairwise, n<8 -> sequential ascending plain.
//  - d2 = (p_sq - 2*cross) + k_sq, left-assoc, plain (2*cross exact).
//  - argmin: first index on ties (ascending interleaved scan, strict '<',
//    lexicographic (d2,id) merge).
__global__ __launch_bounds__(256, 2)
void quant_embed_kernel(const float* __restrict__ pc,
                        const float* __restrict__ keys,
                        const float* __restrict__ values,
                        float* __restrict__ out)
{
#pragma clang fp contract(off)
    __shared__ float4 skeys[MM];   // 64 KiB exactly: (kx,ky,kz,ksq)

    const int tid = threadIdx.x;

    // Stage all keys into LDS; k_sq in ascending-plain order.
    #pragma unroll
    for (int i = 0; i < MM / 256; ++i) {
        const int m = tid + i * 256;
        const float kx = keys[3 * m + 0];
        const float ky = keys[3 * m + 1];
        const float kz = keys[3 * m + 2];
        const float ksq = ((kx * kx) + (ky * ky)) + (kz * kz);
        skeys[m] = make_float4(kx, ky, kz, ksq);
    }
    __syncthreads();

    const int chunk = tid & 3;
    const int point = blockIdx.x * PTS_PER_BLOCK + (tid >> 2);

    const float px = pc[3 * point + 0];
    const float py = pc[3 * point + 1];
    const float pz = pc[3 * point + 2];
    const float psq = ((px * px) + (py * py)) + (pz * pz);

    float best_d2 = 3.402823466e38f;
    int best_id = 0x7fffffff;

    // Scan keys m = 4k + chunk, k ascending -> strict '<' keeps first index.
    #pragma unroll 8
    for (int k = 0; k < KPC; ++k) {
        const int m = (k << 2) + chunk;
        const float4 K = skeys[m];
        // ascending-plain, no FMA (pragma guarantees no contraction)
        const float cross = ((px * K.x) + (py * K.y)) + (pz * K.z);
        const float d2 = (psq - (2.0f * cross)) + K.w;
        const bool lt = d2 < best_d2;
        best_d2 = lt ? d2 : best_d2;
        best_id = lt ? m : best_id;
    }

    // Butterfly argmin across the 4 chunk lanes; lexicographic (d2, id)
    // reproduces numpy's first-index tie-break exactly.
    #pragma unroll
    for (int off = 1; off <= 2; off <<= 1) {
        const float od = __shfl_xor(best_d2, off);
        const int   oi = __shfl_xor(best_id, off);
        if (od < best_d2 || (od == best_d2 && oi < best_id)) {
            best_d2 = od;
            best_id = oi;
        }
    }

    // Epilogue: 4 lanes cooperatively copy the 64-float value row (float4 x4
    // per lane), lane 0 writes the id (as float), lanes 0..2 write pc rows.
    const float4* vrow = (const float4*)(values + (size_t)best_id * DD);
    float4* of4 = (float4*)(out + FEATS_OFF + (size_t)point * DD);
    #pragma unroll
    for (int j = 0; j < 4; ++j) {
        of4[chunk * 4 + j] = vrow[chunk * 4 + j];
    }
    if (chunk == 0) out[IDS_OFF + point] = (float)best_id;
    if (chunk < 3) {
        out[PC_OFF + 3 * point + chunk] = (chunk == 0) ? px : (chunk == 1 ? py : pz);
    }
}

extern "C" void kernel_launch(void* const* d_in, const int* in_sizes, int n_in,
                              void* d_out, int out_size, void* d_ws, size_t ws_size,
                              hipStream_t stream) {
    const float* pc     = (const float*)d_in[0];
    const float* keys   = (const float*)d_in[1];
    const float* values = (const float*)d_in[2];
    float* out = (float*)d_out;

    dim3 grid(BN / PTS_PER_BLOCK);  // 1024 blocks
    dim3 block(256);
    quant_embed_kernel<<<grid, block, 0, stream>>>(pc, keys, values, out);
}